// Round 2
// baseline (419.656 us; speedup 1.0000x reference)
//
#include <hip/hip_runtime.h>

// Corr1d: corr[b,d,h,x] = sum_c fL[b,c,h,x] * fR[b,c,h,x-d], 0 for x<d.
// Shapes: fL,fR (B=4, C=64, H=256, W=512) fp32; out (B=4, D=48, H=256, W=512) fp32.

#define B_   4
#define C_   64
#define H_   256
#define W_   512
#define DDISP 48

#define WT     128           // x-tile width per block
#define HALO   48            // left halo on fR (covers d up to 47, 4-aligned)
#define CHUNK  32            // channels staged per LDS pass
#define NTHR   192           // 12 d-groups x 16 x-groups

__global__ __launch_bounds__(NTHR, 3)
void corr1d_kernel(const float* __restrict__ fL,
                   const float* __restrict__ fR,
                   float* __restrict__ out)
{
    __shared__ float sL[CHUNK][WT];          // 16 KB
    __shared__ float sR[CHUNK][WT + HALO];   // 22 KB (176 cols)

    const int xt = blockIdx.x;      // 0..3
    const int h  = blockIdx.y;      // 0..255
    const int b  = blockIdx.z;      // 0..3
    const int x0 = xt * WT;

    const int tid = threadIdx.x;
    const int dg  = tid >> 4;       // 0..11  -> d0 = 4*dg
    const int xg  = tid & 15;       // 0..15  -> lx0 = 8*xg
    const int lx0 = xg * 8;
    const int d0  = dg * 4;

    const size_t ch_stride = (size_t)H_ * W_;                  // 131072
    const size_t row_base  = ((size_t)b * C_ * H_ + h) * (size_t)W_;  // [b][0][h][0]

    float acc[4][8];
#pragma unroll
    for (int i = 0; i < 4; ++i)
#pragma unroll
        for (int j = 0; j < 8; ++j) acc[i][j] = 0.f;

    for (int cc = 0; cc < C_; cc += CHUNK) {
        // ---- stage fL chunk: CHUNK x WT floats as float4 ----
        {
            const float4* gL = (const float4*)(fL + row_base + (size_t)cc * ch_stride + x0);
            const int nf4 = CHUNK * (WT / 4);          // 1024
            for (int i = tid; i < nf4; i += NTHR) {
                int c   = i / (WT / 4);
                int col = i % (WT / 4);
                ((float4*)sL)[i] = gL[c * (ch_stride / 4) + col];
            }
        }
        // ---- stage fR chunk: CHUNK x (WT+HALO) floats, zero-fill y<0 ----
        {
            const float4* gR = (const float4*)(fR + row_base + (size_t)cc * ch_stride + (x0 - HALO));
            const int nf4 = CHUNK * ((WT + HALO) / 4); // 32*44 = 1408
            for (int i = tid; i < nf4; i += NTHR) {
                int c   = i / ((WT + HALO) / 4);
                int col = i % ((WT + HALO) / 4);
                int y   = x0 - HALO + col * 4;
                float4 v;
                if (y >= 0) v = gR[c * (ch_stride / 4) + col];
                else        v = make_float4(0.f, 0.f, 0.f, 0.f);
                ((float4*)sR)[c * ((WT + HALO) / 4) + col] = v;
            }
        }
        __syncthreads();

        // ---- compute: 32 FMAs / channel / thread ----
#pragma unroll 4
        for (int c = 0; c < CHUNK; ++c) {
            float fl[8], fr[12];
            *(float4*)&fl[0] = *(const float4*)&sL[c][lx0];
            *(float4*)&fl[4] = *(const float4*)&sL[c][lx0 + 4];
            // fr covers sR[c][lx0 + 44 - d0 .. +12); value j maps to y-index
            // lx0+44-d0+j; needed index for (dd,xx) is j = xx + 4 - dd in [1,11].
            const float* pr = &sR[c][lx0 + (HALO - 4) - d0];
            *(float4*)&fr[0] = *(const float4*)&pr[0];
            *(float4*)&fr[4] = *(const float4*)&pr[4];
            *(float4*)&fr[8] = *(const float4*)&pr[8];
#pragma unroll
            for (int dd = 0; dd < 4; ++dd)
#pragma unroll
                for (int xx = 0; xx < 8; ++xx)
                    acc[dd][xx] = fmaf(fl[xx], fr[xx + 4 - dd], acc[dd][xx]);
        }
        __syncthreads();
    }

    // ---- write out: out[b][d][h][x], float4 x2 per d ----
    const size_t out_base = (((size_t)b * DDISP) * H_ + h) * (size_t)W_;
#pragma unroll
    for (int dd = 0; dd < 4; ++dd) {
        int d = d0 + dd;
        float* po = out + out_base + (size_t)d * ch_stride + x0 + lx0;
        float4 v0 = make_float4(acc[dd][0], acc[dd][1], acc[dd][2], acc[dd][3]);
        float4 v1 = make_float4(acc[dd][4], acc[dd][5], acc[dd][6], acc[dd][7]);
        ((float4*)po)[0] = v0;
        ((float4*)po)[1] = v1;
    }
}

extern "C" void kernel_launch(void* const* d_in, const int* in_sizes, int n_in,
                              void* d_out, int out_size, void* d_ws, size_t ws_size,
                              hipStream_t stream) {
    const float* fL = (const float*)d_in[0];
    const float* fR = (const float*)d_in[1];
    float* out = (float*)d_out;
    dim3 grid(W_ / WT, H_, B_);
    corr1d_kernel<<<grid, dim3(NTHR), 0, stream>>>(fL, fR, out);
}

// Round 5
// 323.298 us; speedup vs baseline: 1.2980x; 1.2980x over previous
//
#include <hip/hip_runtime.h>

// Corr1d: corr[b,d,h,x] = sum_c fL[b,c,h,x] * fR[b,c,h,x-d], 0 for x<d.
// Shapes: fL,fR (B=4, C=64, H=256, W=512) fp32; out (B=4, D=48, H=256, W=512) fp32.
//
// Round 3: conflict-free LDS design. Lane l owns x = x0 + 4l (stride-16B across
// the wave -> every ds_read_b128 spans 1024 contiguous bytes = 0 bank conflicts).
// Wave w owns d in [12w, 12w+12). Per channel/thread: 1 b128 (fL) + 4 b128 (fR)
// feed 48 FMAs (1.67 B per lane-FMA, was 2.5 with 4/8-way conflicts on top).

#define B_    4
#define C_    64
#define H_    256
#define W_    512
#define DDISP 48

#define XT    256            // x-tile per block
#define HALO  48             // fR left halo (d up to 47), 16B-aligned
#define CHUNK 8              // channels staged per LDS pass
#define NTHR  256            // 4 waves; wave w -> d-group, lane l -> x = 4l

__global__ __launch_bounds__(NTHR, 4)
void corr1d_kernel(const float* __restrict__ fL,
                   const float* __restrict__ fR,
                   float* __restrict__ out)
{
    __shared__ float sL[CHUNK][XT];          // 8 KB
    __shared__ float sR[CHUNK][XT + HALO];   // 9.5 KB (304 cols, row = 1216 B, 16B-mult)

    const int xt = blockIdx.x;      // 0..1
    const int h  = blockIdx.y;      // 0..255
    const int b  = blockIdx.z;      // 0..3
    const int x0 = xt * XT;

    const int tid = threadIdx.x;
    const int w   = tid >> 6;       // wave 0..3 -> d0 = 12w
    const int l   = tid & 63;       // lane -> x = x0 + 4l .. +3

    const size_t ch_stride = (size_t)H_ * W_;                       // 131072
    const size_t row_base  = ((size_t)b * C_ * H_ + h) * (size_t)W_;

    float acc[12][4];
#pragma unroll
    for (int i = 0; i < 12; ++i)
#pragma unroll
        for (int j = 0; j < 4; ++j) acc[i][j] = 0.f;

    for (int cc = 0; cc < C_; cc += CHUNK) {
        // ---- stage fL chunk: CHUNK x XT floats, float4, coalesced ----
        {
            const float4* g = (const float4*)(fL + row_base + (size_t)cc * ch_stride + x0);
#pragma unroll
            for (int i = tid; i < CHUNK * (XT / 4); i += NTHR) {   // 512 f4, 2/thread
                int c   = i >> 6;
                int col = i & 63;
                ((float4*)sL)[i] = g[c * (ch_stride / 4) + col];
            }
        }
        // ---- stage fR chunk: CHUNK x (XT+HALO) floats, zero-fill y<0 ----
        {
            for (int i = tid; i < CHUNK * ((XT + HALO) / 4); i += NTHR) { // 608 f4
                int c   = i / ((XT + HALO) / 4);          // /76
                int col = i - c * ((XT + HALO) / 4);
                int y   = x0 - HALO + col * 4;            // fully <0 or fully >=0
                float4 v = make_float4(0.f, 0.f, 0.f, 0.f);
                if (y >= 0)
                    v = *(const float4*)(fR + row_base + (size_t)(cc + c) * ch_stride + y);
                *((float4*)&sR[c][0] + col) = v;
            }
        }
        __syncthreads();

        // ---- compute: per channel 1+4 conflict-free b128 reads, 48 FMAs ----
#pragma unroll 2
        for (int c = 0; c < CHUNK; ++c) {
            float fl[4], fr[16];
            *(float4*)&fl[0] = *(const float4*)&sL[c][4 * l];
            // pr[j] holds global y = x0 + 4l - 12w - 12 + j; need j = xx - dd + 12 in [1,15]
            const float* pr = &sR[c][4 * l - 12 * w + (HALO - 12)];
            *(float4*)&fr[0]  = *(const float4*)&pr[0];
            *(float4*)&fr[4]  = *(const float4*)&pr[4];
            *(float4*)&fr[8]  = *(const float4*)&pr[8];
            *(float4*)&fr[12] = *(const float4*)&pr[12];
#pragma unroll
            for (int dd = 0; dd < 12; ++dd)
#pragma unroll
                for (int xx = 0; xx < 4; ++xx)
                    acc[dd][xx] = fmaf(fl[xx], fr[xx + 12 - dd], acc[dd][xx]);
        }
        __syncthreads();
    }

    // ---- write out[b][12w+dd][h][x0+4l..+3], float4, coalesced per d ----
#pragma unroll
    for (int dd = 0; dd < 12; ++dd) {
        int d = 12 * w + dd;
        float* po = out + (((size_t)b * DDISP + d) * H_ + h) * (size_t)W_ + x0 + 4 * l;
        *(float4*)po = make_float4(acc[dd][0], acc[dd][1], acc[dd][2], acc[dd][3]);
    }
}

extern "C" void kernel_launch(void* const* d_in, const int* in_sizes, int n_in,
                              void* d_out, int out_size, void* d_ws, size_t ws_size,
                              hipStream_t stream) {
    const float* fL = (const float*)d_in[0];
    const float* fR = (const float*)d_in[1];
    float* out = (float*)d_out;
    dim3 grid(W_ / XT, H_, B_);
    corr1d_kernel<<<grid, dim3(NTHR), 0, stream>>>(fL, fR, out);
}